// Round 1
// baseline (1240.031 us; speedup 1.0000x reference)
//
#include <hip/hip_runtime.h>
#include <hip/hip_bf16.h>

// Problem constants (match reference setup_inputs)
#define DD 64
#define LATENT 32
#define OUTD 64

// ---------------------------------------------------------------------------
// Kernel 1: scatter-add edge features into per-node sums + counts.
// One thread per (edge, quad-of-4-floats): 16 threads/edge.
// Edge reads are perfectly coalesced float4; atomics go to sums[r*64+q*4..+3].
// ---------------------------------------------------------------------------
__global__ __launch_bounds__(256) void scatter_kernel(
    const float4* __restrict__ edge4,     // [nEdges*16] float4 view of edge_attr
    const int*    __restrict__ recv,      // [nEdges]
    float*        __restrict__ sums,      // [nNodes*64]
    float*        __restrict__ cnt,       // [nNodes]
    int nEdges)
{
    int t = blockIdx.x * 256 + threadIdx.x;
    int total = nEdges * 16;
    if (t >= total) return;
    int e = t >> 4;          // edge index
    int q = t & 15;          // which float4 of the 64-float row
    int r = recv[e];         // 16 consecutive lanes read the same value (cached)
    float4 v = edge4[t];
    float* dst = sums + (size_t)r * DD + q * 4;
    atomicAdd(dst + 0, v.x);
    atomicAdd(dst + 1, v.y);
    atomicAdd(dst + 2, v.z);
    atomicAdd(dst + 3, v.w);
    if (q == 0) atomicAdd(cnt + r, 1.0f);
}

// ---------------------------------------------------------------------------
// Kernel 2: per-node mean + gather global + MLP (192 -> 32 relu -> 64).
// One thread per node. W1/W2/b1/b2 addresses are wave-uniform -> scalar loads.
// h[32] and o[64] live in VGPRs.
// ---------------------------------------------------------------------------
__global__ __launch_bounds__(256) void mlp_kernel(
    const float* __restrict__ node_attr,   // [nNodes*64]
    const float* __restrict__ sums,        // [nNodes*64]
    const float* __restrict__ cnt,         // [nNodes]
    const float* __restrict__ global_attr, // [nBatch*64]
    const int*   __restrict__ ng_index,    // [nNodes]
    const float* __restrict__ W1,          // [192*32]
    const float* __restrict__ b1,          // [32]
    const float* __restrict__ W2,          // [32*64]
    const float* __restrict__ b2,          // [64]
    float*       __restrict__ out,         // [nNodes*64]
    int nNodes)
{
    int n = blockIdx.x * 256 + threadIdx.x;
    if (n >= nNodes) return;

    float h[LATENT];
#pragma unroll
    for (int j = 0; j < LATENT; ++j) h[j] = b1[j];

    const int   g   = ng_index[n];
    const float inv = 1.0f / fmaxf(cnt[n], 1.0f);

    const float4* a0 = (const float4*)(node_attr   + (size_t)n * DD);
    const float4* a1 = (const float4*)(sums        + (size_t)n * DD);
    const float4* a2 = (const float4*)(global_attr + (size_t)g * DD);

    // Segment 0: node_attr -> W1 rows [0, 64)
#pragma unroll 4
    for (int kk = 0; kk < 16; ++kk) {
        float4 v = a0[kk];
        const float* w = W1 + (kk * 4) * LATENT;
#pragma unroll
        for (int j = 0; j < LATENT; ++j)
            h[j] = fmaf(v.x, w[j],
                   fmaf(v.y, w[LATENT + j],
                   fmaf(v.z, w[2 * LATENT + j],
                   fmaf(v.w, w[3 * LATENT + j], h[j]))));
    }
    // Segment 1: mean of received edges -> W1 rows [64, 128)
#pragma unroll 4
    for (int kk = 0; kk < 16; ++kk) {
        float4 v = a1[kk];
        v.x *= inv; v.y *= inv; v.z *= inv; v.w *= inv;
        const float* w = W1 + (DD + kk * 4) * LATENT;
#pragma unroll
        for (int j = 0; j < LATENT; ++j)
            h[j] = fmaf(v.x, w[j],
                   fmaf(v.y, w[LATENT + j],
                   fmaf(v.z, w[2 * LATENT + j],
                   fmaf(v.w, w[3 * LATENT + j], h[j]))));
    }
    // Segment 2: gathered global attr -> W1 rows [128, 192)
#pragma unroll 4
    for (int kk = 0; kk < 16; ++kk) {
        float4 v = a2[kk];
        const float* w = W1 + (2 * DD + kk * 4) * LATENT;
#pragma unroll
        for (int j = 0; j < LATENT; ++j)
            h[j] = fmaf(v.x, w[j],
                   fmaf(v.y, w[LATENT + j],
                   fmaf(v.z, w[2 * LATENT + j],
                   fmaf(v.w, w[3 * LATENT + j], h[j]))));
    }

    // ReLU
#pragma unroll
    for (int j = 0; j < LATENT; ++j) h[j] = fmaxf(h[j], 0.0f);

    // Second layer: out = h @ W2 + b2
    float o[OUTD];
#pragma unroll
    for (int t = 0; t < OUTD; ++t) o[t] = b2[t];
#pragma unroll 4
    for (int j = 0; j < LATENT; ++j) {
        const float hj = h[j];
        const float* w = W2 + j * OUTD;
#pragma unroll
        for (int t = 0; t < OUTD; ++t) o[t] = fmaf(hj, w[t], o[t]);
    }

    float4* outp = (float4*)(out + (size_t)n * OUTD);
#pragma unroll
    for (int qq = 0; qq < 16; ++qq) {
        outp[qq] = make_float4(o[4 * qq + 0], o[4 * qq + 1],
                               o[4 * qq + 2], o[4 * qq + 3]);
    }
}

extern "C" void kernel_launch(void* const* d_in, const int* in_sizes, int n_in,
                              void* d_out, int out_size, void* d_ws, size_t ws_size,
                              hipStream_t stream)
{
    const float* node_attr   = (const float*)d_in[0];
    const float* edge_attr   = (const float*)d_in[1];
    const float* global_attr = (const float*)d_in[2];
    const float* W1          = (const float*)d_in[3];
    const float* b1          = (const float*)d_in[4];
    const float* W2          = (const float*)d_in[5];
    const float* b2          = (const float*)d_in[6];
    const int*   recv        = (const int*)d_in[7];
    const int*   ng_index    = (const int*)d_in[8];
    float*       out         = (float*)d_out;

    const int nNodes = in_sizes[0] / DD;
    const int nEdges = in_sizes[1] / DD;

    // Workspace layout: sums [nNodes*64] f32, cnt [nNodes] f32
    float* sums = (float*)d_ws;
    float* cnt  = sums + (size_t)nNodes * DD;
    const size_t zero_bytes = (size_t)nNodes * DD * sizeof(float)
                            + (size_t)nNodes * sizeof(float);

    // Zero the accumulators (ws is re-poisoned to 0xAA before every launch).
    hipMemsetAsync(d_ws, 0, zero_bytes, stream);

    // Scatter-add edges.
    {
        int total  = nEdges * 16;
        int blocks = (total + 255) / 256;
        scatter_kernel<<<blocks, 256, 0, stream>>>(
            (const float4*)edge_attr, recv, sums, cnt, nEdges);
    }

    // Mean + gather + MLP.
    {
        int blocks = (nNodes + 255) / 256;
        mlp_kernel<<<blocks, 256, 0, stream>>>(
            node_attr, sums, cnt, global_attr, ng_index,
            W1, b1, W2, b2, out, nNodes);
    }
}

// Round 2
// 599.931 us; speedup vs baseline: 2.0670x; 2.0670x over previous
//
#include <hip/hip_runtime.h>
#include <hip/hip_bf16.h>

#define DD 64
#define LATENT 32
#define OUTD 64
#define SCAN_TILE 1024   // items per block in the scan (256 thr x 4)

// ---------------------------------------------------------------------------
// 1) Histogram: counts[r] = #edges received by node r.  1M int atomics.
// ---------------------------------------------------------------------------
__global__ __launch_bounds__(256) void hist_kernel(
    const int* __restrict__ recv, int* __restrict__ counts, int nEdges)
{
    int e = blockIdx.x * 256 + threadIdx.x;
    if (e < nEdges) atomicAdd(&counts[recv[e]], 1);
}

// ---------------------------------------------------------------------------
// 2a) Scan pass 1: per-block (1024 items) reduction -> bsum[block]
// ---------------------------------------------------------------------------
__global__ __launch_bounds__(256) void scan_reduce_kernel(
    const int* __restrict__ counts, int* __restrict__ bsum, int n)
{
    __shared__ int l[256];
    int tid = threadIdx.x;
    int base = blockIdx.x * SCAN_TILE + tid * 4;
    int s = 0;
#pragma unroll
    for (int i = 0; i < 4; ++i)
        if (base + i < n) s += counts[base + i];
    l[tid] = s;
    __syncthreads();
    for (int d = 128; d > 0; d >>= 1) {
        if (tid < d) l[tid] += l[tid + d];
        __syncthreads();
    }
    if (tid == 0) bsum[blockIdx.x] = l[0];
}

// ---------------------------------------------------------------------------
// 2b) Scan pass 2: exclusive scan of bsum[nb] in one block (nb <= 256)
// ---------------------------------------------------------------------------
__global__ __launch_bounds__(256) void scan_blocks_kernel(
    int* __restrict__ bsum, int nb)
{
    __shared__ int sc[2][256];
    int tid = threadIdx.x;
    int v = (tid < nb) ? bsum[tid] : 0;
    int orig = v;
    sc[0][tid] = v;
    __syncthreads();
    int src = 0;
#pragma unroll
    for (int d = 1; d < 256; d <<= 1) {
        int x = sc[src][tid];
        if (tid >= d) x += sc[src][tid - d];
        sc[src ^ 1][tid] = x;
        src ^= 1;
        __syncthreads();
    }
    if (tid < nb) bsum[tid] = sc[src][tid] - orig;   // exclusive
}

// ---------------------------------------------------------------------------
// 2c) Scan pass 3: per-block exclusive scan + block offset -> offsets, cursor
// ---------------------------------------------------------------------------
__global__ __launch_bounds__(256) void scan_final_kernel(
    const int* __restrict__ counts, const int* __restrict__ bsum,
    int* __restrict__ offsets, int* __restrict__ cursor, int n)
{
    __shared__ int sc[2][256];
    int tid = threadIdx.x;
    int base = blockIdx.x * SCAN_TILE + tid * 4;
    int c[4];
    int s = 0;
#pragma unroll
    for (int i = 0; i < 4; ++i) {
        c[i] = (base + i < n) ? counts[base + i] : 0;
        s += c[i];
    }
    sc[0][tid] = s;
    __syncthreads();
    int src = 0;
#pragma unroll
    for (int d = 1; d < 256; d <<= 1) {
        int x = sc[src][tid];
        if (tid >= d) x += sc[src][tid - d];
        sc[src ^ 1][tid] = x;
        src ^= 1;
        __syncthreads();
    }
    int run = bsum[blockIdx.x] + sc[src][tid] - s;   // exclusive prefix
#pragma unroll
    for (int i = 0; i < 4; ++i) {
        if (base + i < n) {
            offsets[base + i] = run;
            cursor[base + i]  = run;
        }
        run += c[i];
    }
}

// ---------------------------------------------------------------------------
// 3) Place edges into CSR buckets. 1M int atomics + 4 MB writes.
// ---------------------------------------------------------------------------
__global__ __launch_bounds__(256) void place_kernel(
    const int* __restrict__ recv, int* __restrict__ cursor,
    int* __restrict__ edge_ids, int nEdges)
{
    int e = blockIdx.x * 256 + threadIdx.x;
    if (e < nEdges) {
        int r = recv[e];
        int idx = atomicAdd(&cursor[r], 1);
        edge_ids[idx] = e;
    }
}

// ---------------------------------------------------------------------------
// 4) Gather: one wave per node, lane = feature. Writes MEAN into out rows
//    (out reused as scratch; mlp_kernel later reads then overwrites row n
//    from thread n only -> safe).
// ---------------------------------------------------------------------------
__global__ __launch_bounds__(256) void gather_kernel(
    const float* __restrict__ edge_attr,   // [nEdges*64]
    const int*   __restrict__ edge_ids,    // [nEdges] CSR order
    const int*   __restrict__ offsets,     // [nNodes]
    const int*   __restrict__ counts,      // [nNodes]
    float*       __restrict__ out,         // [nNodes*64] <- mean written here
    int nNodes)
{
    int wave = (blockIdx.x * 256 + threadIdx.x) >> 6;
    int lane = threadIdx.x & 63;
    if (wave >= nNodes) return;
    int start = offsets[wave];
    int cnt   = counts[wave];
    float s0 = 0.0f, s1 = 0.0f;
    int i = 0;
    for (; i + 1 < cnt; i += 2) {
        int e0 = edge_ids[start + i];
        int e1 = edge_ids[start + i + 1];
        s0 += edge_attr[(size_t)e0 * DD + lane];
        s1 += edge_attr[(size_t)e1 * DD + lane];
    }
    if (i < cnt) s0 += edge_attr[(size_t)edge_ids[start + i] * DD + lane];
    float inv = 1.0f / (float)max(cnt, 1);
    out[(size_t)wave * DD + lane] = (s0 + s1) * inv;
}

// ---------------------------------------------------------------------------
// 5) MLP: one thread per node. Reads mean from io (d_out), overwrites with
//    final output. Layer 2 chunked into 16 outputs to cap VGPR pressure.
// ---------------------------------------------------------------------------
__global__ __launch_bounds__(256) void mlp_kernel(
    const float* __restrict__ node_attr,   // [nNodes*64]
    const float* __restrict__ global_attr, // [nBatch*64]
    const int*   __restrict__ ng_index,    // [nNodes]
    const float* __restrict__ W1,          // [192*32]
    const float* __restrict__ b1,          // [32]
    const float* __restrict__ W2,          // [32*64]
    const float* __restrict__ b2,          // [64]
    float*                    io,          // [nNodes*64] mean in, out out
    int nNodes)
{
    int n = blockIdx.x * 256 + threadIdx.x;
    if (n >= nNodes) return;

    float h[LATENT];
#pragma unroll
    for (int j = 0; j < LATENT; ++j) h[j] = b1[j];

    const int g = ng_index[n];
    const float4* a0 = (const float4*)(node_attr   + (size_t)n * DD);
    const float4* a1 = (const float4*)(io          + (size_t)n * DD);
    const float4* a2 = (const float4*)(global_attr + (size_t)g * DD);

    for (int kk = 0; kk < 16; ++kk) {
        float4 v = a0[kk];
        const float* w = W1 + (kk * 4) * LATENT;
#pragma unroll
        for (int j = 0; j < LATENT; ++j)
            h[j] = fmaf(v.x, w[j],
                   fmaf(v.y, w[LATENT + j],
                   fmaf(v.z, w[2 * LATENT + j],
                   fmaf(v.w, w[3 * LATENT + j], h[j]))));
    }
    for (int kk = 0; kk < 16; ++kk) {
        float4 v = a1[kk];
        const float* w = W1 + (DD + kk * 4) * LATENT;
#pragma unroll
        for (int j = 0; j < LATENT; ++j)
            h[j] = fmaf(v.x, w[j],
                   fmaf(v.y, w[LATENT + j],
                   fmaf(v.z, w[2 * LATENT + j],
                   fmaf(v.w, w[3 * LATENT + j], h[j]))));
    }
    for (int kk = 0; kk < 16; ++kk) {
        float4 v = a2[kk];
        const float* w = W1 + (2 * DD + kk * 4) * LATENT;
#pragma unroll
        for (int j = 0; j < LATENT; ++j)
            h[j] = fmaf(v.x, w[j],
                   fmaf(v.y, w[LATENT + j],
                   fmaf(v.z, w[2 * LATENT + j],
                   fmaf(v.w, w[3 * LATENT + j], h[j]))));
    }

#pragma unroll
    for (int j = 0; j < LATENT; ++j) h[j] = fmaxf(h[j], 0.0f);

    float4* outp = (float4*)(io + (size_t)n * OUTD);
#pragma unroll
    for (int c0 = 0; c0 < OUTD; c0 += 16) {
        float o[16];
#pragma unroll
        for (int t = 0; t < 16; ++t) o[t] = b2[c0 + t];
        for (int j = 0; j < LATENT; ++j) {
            const float hj = h[j];
            const float* w = W2 + j * OUTD + c0;
#pragma unroll
            for (int t = 0; t < 16; ++t) o[t] = fmaf(hj, w[t], o[t]);
        }
#pragma unroll
        for (int q = 0; q < 4; ++q)
            outp[c0 / 4 + q] = make_float4(o[4*q], o[4*q+1], o[4*q+2], o[4*q+3]);
    }
}

extern "C" void kernel_launch(void* const* d_in, const int* in_sizes, int n_in,
                              void* d_out, int out_size, void* d_ws, size_t ws_size,
                              hipStream_t stream)
{
    const float* node_attr   = (const float*)d_in[0];
    const float* edge_attr   = (const float*)d_in[1];
    const float* global_attr = (const float*)d_in[2];
    const float* W1          = (const float*)d_in[3];
    const float* b1          = (const float*)d_in[4];
    const float* W2          = (const float*)d_in[5];
    const float* b2          = (const float*)d_in[6];
    const int*   recv        = (const int*)d_in[7];
    const int*   ng_index    = (const int*)d_in[8];
    float*       out         = (float*)d_out;

    const int nNodes = in_sizes[0] / DD;
    const int nEdges = in_sizes[1] / DD;
    const int nb     = (nNodes + SCAN_TILE - 1) / SCAN_TILE;   // scan blocks (98)

    // ws layout (ints): counts[n] | offsets[n] | cursor[n] | bsum[256] | edge_ids[nEdges]
    int* counts   = (int*)d_ws;
    int* offsets  = counts  + nNodes;
    int* cursor   = offsets + nNodes;
    int* bsum     = cursor  + nNodes;
    int* edge_ids = bsum    + 256;

    hipMemsetAsync(counts, 0, (size_t)nNodes * sizeof(int), stream);

    hist_kernel<<<(nEdges + 255) / 256, 256, 0, stream>>>(recv, counts, nEdges);
    scan_reduce_kernel<<<nb, 256, 0, stream>>>(counts, bsum, nNodes);
    scan_blocks_kernel<<<1, 256, 0, stream>>>(bsum, nb);
    scan_final_kernel<<<nb, 256, 0, stream>>>(counts, bsum, offsets, cursor, nNodes);
    place_kernel<<<(nEdges + 255) / 256, 256, 0, stream>>>(recv, cursor, edge_ids, nEdges);

    gather_kernel<<<(nNodes + 3) / 4, 256, 0, stream>>>(
        edge_attr, edge_ids, offsets, counts, out, nNodes);

    mlp_kernel<<<(nNodes + 255) / 256, 256, 0, stream>>>(
        node_attr, global_attr, ng_index, W1, b1, W2, b2, out, nNodes);
}